// Round 1
// baseline (117.920 us; speedup 1.0000x reference)
//
#include <hip/hip_runtime.h>
#include <math.h>

#define HH 512
#define WW 512
#define NA 180
#define ND 729
#define NB 2

// ws layout (float units):
//   [0, 729)                 g (spatial filter kernel)
//   [1024, 1024+180)         cos table
//   [1280, 1280+180)         sin table
//   [2048, 2048 + NB*NA*ND)  filtered sinograms
#define WS_COS 1024
#define WS_SIN 1280
#define WS_FILT 2048

// g[n] = (1/D) * [0.25 - sum_{odd k} cos(2*pi*k*n/D)/(pi^2 k^2)]
// exact phase reduction via (k*n) mod D, double-precision cos.
__global__ __launch_bounds__(64) void k_gtab(float* __restrict__ ws) {
    int n = blockIdx.x;          // 0..728
    int lane = threadIdx.x;      // 0..63
    double acc = 0.0;
    for (int j = lane; j < 364; j += 64) {
        int k = 2 * j + 1;
        int t = (k * n) % ND;
        double ang = (2.0 * M_PI) * (double)t / (double)ND;
        acc -= cos(ang) / (M_PI * M_PI * (double)k * (double)k);
    }
    // wave-64 butterfly reduce
    for (int off = 32; off > 0; off >>= 1)
        acc += __shfl_down(acc, off, 64);
    if (lane == 0) {
        acc += 0.25;
        ws[n] = (float)(acc / (double)ND);
    }
}

__global__ __launch_bounds__(256) void k_angles(float* __restrict__ ws) {
    int t = threadIdx.x;
    if (t < NA) {
        double ang = M_PI * (double)t / (double)(NA - 1);  // linspace(0, pi, 180)
        ws[WS_COS + t] = (float)cos(ang);
        ws[WS_SIN + t] = (float)sin(ang);
    }
}

// circular convolution: filtered[row][n] = sum_m x[row][m] * g[(n-m) mod D]
__global__ __launch_bounds__(256) void k_filter(const float* __restrict__ sino,
                                                float* __restrict__ ws) {
    __shared__ float xs[ND];
    __shared__ float g2[1536];   // g duplicated; padded (reads past 1458 only for unused lanes)
    int row = blockIdx.x;        // b*NA + a
    const float* x = sino + row * ND;
    for (int i = threadIdx.x; i < ND; i += 256) {
        float gv = ws[i];
        xs[i] = x[i];
        g2[i] = gv;
        g2[i + ND] = gv;
    }
    __syncthreads();
    int n0 = threadIdx.x, n1 = n0 + 256, n2 = n0 + 512;
    float acc0 = 0.f, acc1 = 0.f, acc2 = 0.f;
    for (int m = 0; m < ND; ++m) {
        float xv = xs[m];
        acc0 += xv * g2[n0 - m + ND];
        acc1 += xv * g2[n1 - m + ND];
        acc2 += xv * g2[n2 - m + ND];
    }
    float* f = ws + WS_FILT + row * ND;
    f[n0] = acc0;
    f[n1] = acc1;
    if (n2 < ND) f[n2] = acc2;
}

__global__ __launch_bounds__(256) void k_bp(const float* __restrict__ ws,
                                            float* __restrict__ out) {
    __shared__ float cs[NA], sn[NA];
    int tid = threadIdx.x;
    if (tid < NA) { cs[tid] = ws[WS_COS + tid]; sn[tid] = ws[WS_SIN + tid]; }
    __syncthreads();
    int p = blockIdx.x * 256 + tid;       // < NB*HH*WW
    int b = p / (HH * WW);
    int rem = p - b * (HH * WW);
    int y = rem / WW;
    int x = rem - y * WW;
    float xc = (float)x - (WW * 0.5f);
    float yc = (float)y - (HH * 0.5f);
    const float* f = ws + WS_FILT + b * (NA * ND);
    float acc = 0.f;
    #pragma unroll 4
    for (int a = 0; a < NA; ++a) {
        float rot = xc * cs[a] + yc * sn[a];
        float t = (rot * 0.15915494309189535f) * 729.0f;  // rot/(2pi)*D
        int i = (int)t;                                   // trunc toward zero, matches astype(int32)
        i = i < 0 ? 0 : (i > (ND - 1) ? (ND - 1) : i);
        acc += f[a * ND + i];
    }
    out[p] = fmaxf(acc * (float)(M_PI / NA), 0.0f);       // clip(·, 0, max) == relu (max >= 0)
}

extern "C" void kernel_launch(void* const* d_in, const int* in_sizes, int n_in,
                              void* d_out, int out_size, void* d_ws, size_t ws_size,
                              hipStream_t stream) {
    const float* sino = (const float*)d_in[0];
    float* out = (float*)d_out;
    float* ws = (float*)d_ws;

    hipLaunchKernelGGL(k_gtab,   dim3(ND), dim3(64), 0, stream, ws);
    hipLaunchKernelGGL(k_angles, dim3(1), dim3(256), 0, stream, ws);
    hipLaunchKernelGGL(k_filter, dim3(NB * NA), dim3(256), 0, stream, sino, ws);
    hipLaunchKernelGGL(k_bp, dim3((NB * HH * WW) / 256), dim3(256), 0, stream, ws, out);
}